// Round 1
// baseline (179.760 us; speedup 1.0000x reference)
//
#include <hip/hip_runtime.h>
#include <stdint.h>

typedef float f32x4 __attribute__((ext_vector_type(4)));
typedef short s16x8 __attribute__((ext_vector_type(8)));

#define NPTS 4096
#define DDIM 512
#define NF   24
#define NBLK 32   // 4096 / 128

// ---------------- ws layout ----------------
// [0, 4194304)            : E as bf16 (4096*512*2)
// [4194304, +16384)       : sq[4096] f32 (exact fp32 row sum-of-squares)
// [+16384, +16)           : mm[2] : d2min bits, d2max bits (nonneg float as uint)
// [..., +393216)          : deg[4096][24] f32

// ---------------- init ----------------
__global__ __launch_bounds__(256) void k_init(float* __restrict__ deg,
                                              unsigned* __restrict__ mm) {
    int i = blockIdx.x * 256 + threadIdx.x;
    if (i < NPTS * NF) deg[i] = 0.0f;
    if (i == 0) { mm[0] = 0x7F7FFFFFu; mm[1] = 0u; }
}

// ---------------- convert f32 -> bf16 (RNE), rowwise sum of squares ----------------
__global__ __launch_bounds__(256) void k_convert(const float* __restrict__ in,
                                                 ushort* __restrict__ Eb,
                                                 float* __restrict__ sq) {
    const int w = threadIdx.x >> 6, lane = threadIdx.x & 63;
    const int row = blockIdx.x * 4 + w;
    const float* src = in + (size_t)row * DDIM + lane * 8;
    float4 a = ((const float4*)src)[0];
    float4 b = ((const float4*)src)[1];
    float v[8] = {a.x, a.y, a.z, a.w, b.x, b.y, b.z, b.w};
    unsigned u[8];
    float ss = 0.0f;
#pragma unroll
    for (int i = 0; i < 8; ++i) {
        ss += v[i] * v[i];
        unsigned bits = __float_as_uint(v[i]);
        u[i] = (bits + 0x7FFFu + ((bits >> 16) & 1u)) >> 16;  // RNE to bf16
    }
    uint4 pk;
    pk.x = u[0] | (u[1] << 16);
    pk.y = u[2] | (u[3] << 16);
    pk.z = u[4] | (u[5] << 16);
    pk.w = u[6] | (u[7] << 16);
    *(uint4*)(Eb + (size_t)row * DDIM + lane * 8) = pk;
#pragma unroll
    for (int s = 1; s < 64; s <<= 1) ss += __shfl_xor(ss, s);
    if (lane == 0) sq[row] = ss;
}

// ---------------- shared 128x128 Gram tile (bf16 MFMA 16x16x32) ----------------
// Output mapping (swapped operands): for wave w, lane (g = lane>>4, l15 = lane&15):
//   acc[bi][bj][m] = dot(E[rb*128 + w*32 + bi*16 + l15], E[cb*128 + bj*16 + g*4 + m])
__device__ __forceinline__ void gram_tile(const ushort* __restrict__ Eb, int rb, int cb,
                                          ushort* As, ushort* Bs, f32x4 acc[2][8]) {
    const int tid = threadIdx.x;
    const int w = tid >> 6, lane = tid & 63, g = lane >> 4, l15 = lane & 15;
#pragma unroll 1
    for (int kk = 0; kk < DDIM / 32; ++kk) {
        const int k0 = kk * 32;
        __syncthreads();
#pragma unroll
        for (int it = 0; it < 2; ++it) {
            int li  = it * 256 + tid;          // 0..511 : 128 rows x 4 chunks of 8 bf16
            int row = li >> 2, ch = li & 3;
            uint4 va = *(const uint4*)(Eb + (size_t)(rb * 128 + row) * DDIM + k0 + ch * 8);
            uint4 vb = *(const uint4*)(Eb + (size_t)(cb * 128 + row) * DDIM + k0 + ch * 8);
            *(uint4*)(As + row * 32 + ch * 8) = va;
            *(uint4*)(Bs + row * 32 + ch * 8) = vb;
        }
        __syncthreads();
        s16x8 rf0 = *(const s16x8*)(As + (w * 32 + 0 * 16 + l15) * 32 + g * 8);
        s16x8 rf1 = *(const s16x8*)(As + (w * 32 + 1 * 16 + l15) * 32 + g * 8);
#pragma unroll
        for (int bj = 0; bj < 8; ++bj) {
            s16x8 cf = *(const s16x8*)(Bs + (bj * 16 + l15) * 32 + g * 8);
            acc[0][bj] = __builtin_amdgcn_mfma_f32_16x16x32_bf16(cf, rf0, acc[0][bj], 0, 0, 0);
            acc[1][bj] = __builtin_amdgcn_mfma_f32_16x16x32_bf16(cf, rf1, acc[1][bj], 0, 0, 0);
        }
    }
}

// ---------------- pass 1: min/max of off-diag squared distance ----------------
__global__ __launch_bounds__(256) void k_minmax(const ushort* __restrict__ Eb,
                                                const float* __restrict__ sq,
                                                unsigned* __restrict__ mm) {
    const int rb = blockIdx.y, cb = blockIdx.x;
    if (cb < rb) return;  // symmetric: upper triangle only
    __shared__ ushort As[128 * 32], Bs[128 * 32];
    __shared__ float sqr[128], sqc[128];
    __shared__ float red[8];
    const int tid = threadIdx.x;
    if (tid < 128) sqr[tid] = sq[rb * 128 + tid];
    else           sqc[tid - 128] = sq[cb * 128 + (tid - 128)];
    f32x4 acc[2][8];
#pragma unroll
    for (int bi = 0; bi < 2; ++bi)
#pragma unroll
        for (int bj = 0; bj < 8; ++bj) acc[bi][bj] = (f32x4){0.f, 0.f, 0.f, 0.f};
    gram_tile(Eb, rb, cb, As, Bs, acc);
    const int w = tid >> 6, lane = tid & 63, g = lane >> 4, l15 = lane & 15;
    const float sr0 = sqr[w * 32 + l15], sr1 = sqr[w * 32 + 16 + l15];
    float mn = 3.4e38f, mx = 0.0f;
#pragma unroll
    for (int bi = 0; bi < 2; ++bi)
#pragma unroll
        for (int bj = 0; bj < 8; ++bj)
#pragma unroll
            for (int m = 0; m < 4; ++m) {
                int tr = w * 32 + bi * 16 + l15;
                int tc = bj * 16 + g * 4 + m;
                float d2 = (bi ? sr1 : sr0) + sqc[tc] - 2.0f * acc[bi][bj][m];
                d2 = fmaxf(d2, 0.0f);
                bool diag = (rb == cb) && (tr == tc);
                mn = diag ? mn : fminf(mn, d2);
                mx = diag ? mx : fmaxf(mx, d2);
            }
#pragma unroll
    for (int s = 1; s < 64; s <<= 1) {
        mn = fminf(mn, __shfl_xor(mn, s));
        mx = fmaxf(mx, __shfl_xor(mx, s));
    }
    if (lane == 0) { red[w] = mn; red[4 + w] = mx; }
    __syncthreads();
    if (tid == 0) {
        mn = fminf(fminf(red[0], red[1]), fminf(red[2], red[3]));
        mx = fmaxf(fmaxf(red[4], red[5]), fmaxf(red[6], red[7]));
        atomicMin(&mm[0], __float_as_uint(mn));  // nonneg floats: bit order == value order
        atomicMax(&mm[1], __float_as_uint(mx));
    }
}

// ---------------- pass 2: 24-filtration sigmoid accumulation into deg ----------------
__global__ __launch_bounds__(256) void k_accum(const ushort* __restrict__ Eb,
                                               const float* __restrict__ sq,
                                               const unsigned* __restrict__ mm,
                                               float* __restrict__ deg) {
    const int rb = blockIdx.y, cb = blockIdx.x;
    __shared__ ushort As[128 * 32], Bs[128 * 32];
    __shared__ float sqr[128], sqc[128];
    __shared__ float degr[128][NF];
    const int tid = threadIdx.x;
    if (tid < 128) sqr[tid] = sq[rb * 128 + tid];
    else           sqc[tid - 128] = sq[cb * 128 + (tid - 128)];
    for (int i = tid; i < 128 * NF; i += 256) ((float*)degr)[i] = 0.0f;
    f32x4 acc[2][8];
#pragma unroll
    for (int bi = 0; bi < 2; ++bi)
#pragma unroll
        for (int bj = 0; bj < 8; ++bj) acc[bi][bj] = (f32x4){0.f, 0.f, 0.f, 0.f};
    gram_tile(Eb, rb, cb, As, Bs, acc);
    const int w = tid >> 6, lane = tid & 63, g = lane >> 4, l15 = lane & 15;

    const float dmin2 = __uint_as_float(mm[0]);
    const float dmax2 = __uint_as_float(mm[1]);
    const float d_min = dmin2 > 1e-12f ? sqrtf(dmin2) : 0.0f;
    const float d_mx  = dmax2 > 1e-12f ? sqrtf(dmax2) : 0.0f;
    const float d_max = fmaxf(d_mx, d_min + 1e-4f);
    const float stp   = (d_max - d_min) / 23.0f;
    const float invt  = 1.0f / 0.15f;

    const float sr0 = sqr[w * 32 + l15], sr1 = sqr[w * 32 + 16 + l15];
    float b[2][8][4];  // d * invt, fully unrolled -> registers
#pragma unroll
    for (int bi = 0; bi < 2; ++bi)
#pragma unroll
        for (int bj = 0; bj < 8; ++bj)
#pragma unroll
            for (int m = 0; m < 4; ++m) {
                int tr = w * 32 + bi * 16 + l15;
                int tc = bj * 16 + g * 4 + m;
                float d2 = (bi ? sr1 : sr0) + sqc[tc] - 2.0f * acc[bi][bj][m];
                d2 = fmaxf(d2, 0.0f);
                float d = d2 > 1e-12f ? sqrtf(d2) : 0.0f;  // matches ref's safe-sqrt
                if (rb == cb && tr == tc) d = 1e9f;         // diag pushed to 'infinity'
                b[bi][bj][m] = d * invt;
            }

#pragma unroll 1
    for (int t = 0; t < NF; ++t) {
        const float tcs = (d_min + t * stp) * invt;
        float rs0 = 0.0f, rs1 = 0.0f;
#pragma unroll
        for (int bj = 0; bj < 8; ++bj)
#pragma unroll
            for (int m = 0; m < 4; ++m) {
                // sigmoid((t - d)/T) = 1 / (1 + exp((d - t)/T)); saturates safely (inf -> 0)
                rs0 += __builtin_amdgcn_rcpf(1.0f + __expf(b[0][bj][m] - tcs));
                rs1 += __builtin_amdgcn_rcpf(1.0f + __expf(b[1][bj][m] - tcs));
            }
        // row sums: reduce across the 4 g-groups (cols are lane-local)
        rs0 += __shfl_xor(rs0, 16); rs0 += __shfl_xor(rs0, 32);
        rs1 += __shfl_xor(rs1, 16); rs1 += __shfl_xor(rs1, 32);
        if (g == 0) {
            degr[w * 32 + l15][t]      += rs0;   // distinct rows per wave/lane: no race
            degr[w * 32 + 16 + l15][t] += rs1;
        }
    }
    __syncthreads();
    for (int i = tid; i < 128 * NF; i += 256) {
        int r = i / NF, t = i % NF;
        atomicAdd(&deg[(size_t)(rb * 128 + r) * NF + t], degr[r][t]);
    }
}

// ---------------- finalize ----------------
__global__ __launch_bounds__(256) void k_final(const float* __restrict__ deg,
                                               float* __restrict__ out) {
    const int tid = threadIdx.x;
    float s[NF], cnt[8];
#pragma unroll
    for (int t = 0; t < NF; ++t) s[t] = 0.0f;
#pragma unroll
    for (int k = 0; k < 8; ++k) cnt[k] = 0.0f;
    for (int i = tid; i < NPTS; i += 256) {
        const float* row = deg + (size_t)i * NF;
#pragma unroll
        for (int t = 0; t < NF; ++t) {
            float v = row[t];
            s[t] += v;
            if (t >= 16) cnt[t - 16] += (v < 0.5f) ? 1.0f : 0.0f;
        }
    }
#pragma unroll
    for (int t = 0; t < NF; ++t)
#pragma unroll
        for (int o = 1; o < 64; o <<= 1) s[t] += __shfl_xor(s[t], o);
#pragma unroll
    for (int k = 0; k < 8; ++k)
#pragma unroll
        for (int o = 1; o < 64; o <<= 1) cnt[k] += __shfl_xor(cnt[k], o);
    __shared__ float red[4][32];
    const int w = tid >> 6, lane = tid & 63;
    if (lane == 0) {
#pragma unroll
        for (int t = 0; t < NF; ++t) red[w][t] = s[t];
#pragma unroll
        for (int k = 0; k < 8; ++k) red[w][NF + k] = cnt[k];
    }
    __syncthreads();
    if (tid == 0) {
        float h0 = 0.0f, h1 = 0.0f;
#pragma unroll
        for (int t = 0; t < NF; ++t) {
            float S = red[0][t] + red[1][t] + red[2][t] + red[3][t];  // sum_{i!=j} adj
            float edges = S * 0.5f;
            h1 += fmaxf(edges - (float)(NPTS - 1), 0.0f) / (float)NPTS;
        }
#pragma unroll
        for (int k = 0; k < 8; ++k)
            h0 += red[0][NF + k] + red[1][NF + k] + red[2][NF + k] + red[3][NF + k];
        h0 *= (1.0f / 8.0f);
        h1 *= (1.0f / 24.0f);
        out[0] = (h0 + 0.5f * h1) * 0.1f;
    }
}

extern "C" void kernel_launch(void* const* d_in, const int* in_sizes, int n_in,
                              void* d_out, int out_size, void* d_ws, size_t ws_size,
                              hipStream_t stream) {
    (void)in_sizes; (void)n_in; (void)out_size; (void)ws_size;
    const float* emb = (const float*)d_in[0];
    uint8_t* ws = (uint8_t*)d_ws;
    ushort*   Eb  = (ushort*)(ws);
    float*    sqv = (float*)(ws + 4194304);
    unsigned* mm  = (unsigned*)(ws + 4194304 + 16384);
    float*    deg = (float*)(ws + 4194304 + 16384 + 16);
    float*    out = (float*)d_out;

    k_init   <<<dim3((NPTS * NF + 255) / 256), dim3(256), 0, stream>>>(deg, mm);
    k_convert<<<dim3(NPTS / 4),                dim3(256), 0, stream>>>(emb, Eb, sqv);
    k_minmax <<<dim3(NBLK, NBLK),              dim3(256), 0, stream>>>(Eb, sqv, mm);
    k_accum  <<<dim3(NBLK, NBLK),              dim3(256), 0, stream>>>(Eb, sqv, mm, deg);
    k_final  <<<1, 256, 0, stream>>>(deg, out);
}

// Round 2
// 125.370 us; speedup vs baseline: 1.4338x; 1.4338x over previous
//
#include <hip/hip_runtime.h>
#include <stdint.h>

typedef float f32x4 __attribute__((ext_vector_type(4)));
typedef short s16x8 __attribute__((ext_vector_type(8)));

#define NPTS 4096
#define DDIM 512
#define NF   24
#define NBLK 32   // 4096 / 128

// ---------------- ws layout (shared prefix; D appended for big-ws path) ----
// Eb  @ 0          : 4,194,304  (bf16 E)
// sq  @ 4,194,304  : 16,384     (f32 row sum-of-squares)
// mm  @ 4,210,688  : 64         (d2min bits, d2max bits)
// deg @ 4,210,752  : 393,216    (f32 [4096][24])
// D   @ 4,603,968  : 67,108,864 (f32 [4096][4096] distances, path A only)
#define OFF_SQ  4194304
#define OFF_MM  4210688
#define OFF_DEG 4210752
#define OFF_D   4603968
#define WS_A    71712832ULL

// ---------------- init (deg zero for path B; mm init both paths) -----------
__global__ __launch_bounds__(256) void k_init(float* __restrict__ deg,
                                              unsigned* __restrict__ mm) {
    int i = blockIdx.x * 256 + threadIdx.x;
    if (i < NPTS * NF) deg[i] = 0.0f;
    if (i == 0) { mm[0] = 0x7F7FFFFFu; mm[1] = 0u; }
}

// ---------------- convert f32 -> bf16 (RNE), rowwise sum of squares --------
__global__ __launch_bounds__(256) void k_convert(const float* __restrict__ in,
                                                 ushort* __restrict__ Eb,
                                                 float* __restrict__ sq) {
    const int w = threadIdx.x >> 6, lane = threadIdx.x & 63;
    const int row = blockIdx.x * 4 + w;
    const float* src = in + (size_t)row * DDIM + lane * 8;
    float4 a = ((const float4*)src)[0];
    float4 b = ((const float4*)src)[1];
    float v[8] = {a.x, a.y, a.z, a.w, b.x, b.y, b.z, b.w};
    unsigned u[8];
    float ss = 0.0f;
#pragma unroll
    for (int i = 0; i < 8; ++i) {
        ss += v[i] * v[i];
        unsigned bits = __float_as_uint(v[i]);
        u[i] = (bits + 0x7FFFu + ((bits >> 16) & 1u)) >> 16;  // RNE to bf16
    }
    uint4 pk;
    pk.x = u[0] | (u[1] << 16);
    pk.y = u[2] | (u[3] << 16);
    pk.z = u[4] | (u[5] << 16);
    pk.w = u[6] | (u[7] << 16);
    *(uint4*)(Eb + (size_t)row * DDIM + lane * 8) = pk;
#pragma unroll
    for (int s = 1; s < 64; s <<= 1) ss += __shfl_xor(ss, s);
    if (lane == 0) sq[row] = ss;
}

// ---------------- shared 128x128 Gram tile (bf16 MFMA 16x16x32) ------------
// acc[bi][bj][m] = dot(E[rb*128 + w*32 + bi*16 + l15], E[cb*128 + bj*16 + g*4 + m])
__device__ __forceinline__ void gram_tile(const ushort* __restrict__ Eb, int rb, int cb,
                                          ushort* As, ushort* Bs, f32x4 acc[2][8]) {
    const int tid = threadIdx.x;
    const int w = tid >> 6, lane = tid & 63, g = lane >> 4, l15 = lane & 15;
#pragma unroll 1
    for (int kk = 0; kk < DDIM / 32; ++kk) {
        const int k0 = kk * 32;
        __syncthreads();
#pragma unroll
        for (int it = 0; it < 2; ++it) {
            int li  = it * 256 + tid;          // 0..511 : 128 rows x 4 chunks of 8 bf16
            int row = li >> 2, ch = li & 3;
            uint4 va = *(const uint4*)(Eb + (size_t)(rb * 128 + row) * DDIM + k0 + ch * 8);
            uint4 vb = *(const uint4*)(Eb + (size_t)(cb * 128 + row) * DDIM + k0 + ch * 8);
            *(uint4*)(As + row * 32 + ch * 8) = va;
            *(uint4*)(Bs + row * 32 + ch * 8) = vb;
        }
        __syncthreads();
        s16x8 rf0 = *(const s16x8*)(As + (w * 32 + 0 * 16 + l15) * 32 + g * 8);
        s16x8 rf1 = *(const s16x8*)(As + (w * 32 + 1 * 16 + l15) * 32 + g * 8);
#pragma unroll
        for (int bj = 0; bj < 8; ++bj) {
            s16x8 cf = *(const s16x8*)(Bs + (bj * 16 + l15) * 32 + g * 8);
            acc[0][bj] = __builtin_amdgcn_mfma_f32_16x16x32_bf16(cf, rf0, acc[0][bj], 0, 0, 0);
            acc[1][bj] = __builtin_amdgcn_mfma_f32_16x16x32_bf16(cf, rf1, acc[1][bj], 0, 0, 0);
        }
    }
}

// ============================ PATH A (big ws) ==============================
// pass 1: gram -> d (f32, full matrix via mirror) + global min/max of d2
__global__ __launch_bounds__(256) void k_gramstore(const ushort* __restrict__ Eb,
                                                   const float* __restrict__ sq,
                                                   unsigned* __restrict__ mm,
                                                   float* __restrict__ D) {
    const int rb = blockIdx.y, cb = blockIdx.x;
    if (cb < rb) return;  // upper triangle only; mirror stores fill the rest
    __shared__ ushort As[128 * 32], Bs[128 * 32];
    __shared__ float sqr[128], sqc[128];
    __shared__ float red[8];
    const int tid = threadIdx.x;
    if (tid < 128) sqr[tid] = sq[rb * 128 + tid];
    else           sqc[tid - 128] = sq[cb * 128 + (tid - 128)];
    f32x4 acc[2][8];
#pragma unroll
    for (int bi = 0; bi < 2; ++bi)
#pragma unroll
        for (int bj = 0; bj < 8; ++bj) acc[bi][bj] = (f32x4){0.f, 0.f, 0.f, 0.f};
    gram_tile(Eb, rb, cb, As, Bs, acc);
    const int w = tid >> 6, lane = tid & 63, g = lane >> 4, l15 = lane & 15;
    const float sr0 = sqr[w * 32 + l15], sr1 = sqr[w * 32 + 16 + l15];
    float mn = 3.4e38f, mx = 0.0f;
#pragma unroll
    for (int bi = 0; bi < 2; ++bi) {
        const int tr = rb * 128 + w * 32 + bi * 16 + l15;
        const float sr = bi ? sr1 : sr0;
#pragma unroll
        for (int bj = 0; bj < 8; ++bj) {
            const int tc0 = cb * 128 + bj * 16 + g * 4;
            float dq[4];
#pragma unroll
            for (int m = 0; m < 4; ++m) {
                int tc = tc0 + m;
                float d2 = sr + sqc[bj * 16 + g * 4 + m] - 2.0f * acc[bi][bj][m];
                d2 = fmaxf(d2, 0.0f);
                bool diag = (tr == tc);
                mn = diag ? mn : fminf(mn, d2);
                mx = diag ? mx : fmaxf(mx, d2);
                float d = d2 > 1e-12f ? sqrtf(d2) : 0.0f;
                dq[m] = diag ? 1e9f : d;
            }
            *(float4*)(D + (size_t)tr * NPTS + tc0) = *(float4*)dq;
            if (rb != cb) {
#pragma unroll
                for (int m = 0; m < 4; ++m)
                    D[(size_t)(tc0 + m) * NPTS + tr] = dq[m];
            }
        }
    }
#pragma unroll
    for (int s = 1; s < 64; s <<= 1) {
        mn = fminf(mn, __shfl_xor(mn, s));
        mx = fmaxf(mx, __shfl_xor(mx, s));
    }
    if (lane == 0) { red[w] = mn; red[4 + w] = mx; }
    __syncthreads();
    if (tid == 0) {
        mn = fminf(fminf(red[0], red[1]), fminf(red[2], red[3]));
        mx = fmaxf(fmaxf(red[4], red[5]), fmaxf(red[6], red[7]));
        atomicMin(&mm[0], __float_as_uint(mn));
        atomicMax(&mm[1], __float_as_uint(mx));
    }
}

// pass 2: stream d, geometric-recurrence sigmoid, 4-way batched rcp.
// Wave = half a row (2048 entries); block = 2 rows x 2 halves.
__global__ __launch_bounds__(256) void k_sig(const float* __restrict__ D,
                                             const unsigned* __restrict__ mm,
                                             float* __restrict__ deg) {
    const int tid = threadIdx.x, w = tid >> 6, lane = tid & 63;
    const int row  = blockIdx.x * 2 + (w >> 1);
    const int half = w & 1;

    const float dmin2 = __uint_as_float(mm[0]);
    const float dmax2 = __uint_as_float(mm[1]);
    const float d_min = dmin2 > 1e-12f ? sqrtf(dmin2) : 0.0f;
    const float d_mx  = dmax2 > 1e-12f ? sqrtf(dmax2) : 0.0f;
    const float d_max = fmaxf(d_mx, d_min + 1e-4f);
    const float stp   = (d_max - d_min) / 23.0f;
    const float S2L   = (1.0f / 0.15f) * 1.44269504f;   // invT * log2(e)
    const float C0    = d_min * S2L;
    const float Ds2   = stp * S2L;
    const float C12   = C0 + 12.0f * Ds2;
    const float R     = __builtin_amdgcn_exp2f(-Ds2);
    const float LIM   = 1073741824.0f;  // 2^30
    const float ECAP  = 125.0f;

    float rs[NF];
#pragma unroll
    for (int k = 0; k < NF; ++k) rs[k] = 0.0f;

    const float4* Drow = (const float4*)(D + (size_t)row * NPTS) + half * 512 + lane;
#pragma unroll 1
    for (int c = 0; c < 8; ++c) {
        float4 dv = Drow[c * 64];
        const float u0 = dv.x * S2L, u1 = dv.y * S2L, u2 = dv.z * S2L, u3 = dv.w * S2L;
        float e0 = __builtin_amdgcn_exp2f(fminf(u0 - C0, ECAP));
        float e1 = __builtin_amdgcn_exp2f(fminf(u1 - C0, ECAP));
        float e2 = __builtin_amdgcn_exp2f(fminf(u2 - C0, ECAP));
        float e3 = __builtin_amdgcn_exp2f(fminf(u3 - C0, ECAP));
#pragma unroll
        for (int k = 0; k < NF; ++k) {
            if (k == 12) {  // re-anchor: fresh exp2 (precision/overflow safety)
                e0 = __builtin_amdgcn_exp2f(fminf(u0 - C12, ECAP));
                e1 = __builtin_amdgcn_exp2f(fminf(u1 - C12, ECAP));
                e2 = __builtin_amdgcn_exp2f(fminf(u2 - C12, ECAP));
                e3 = __builtin_amdgcn_exp2f(fminf(u3 - C12, ECAP));
            }
            float A  = 1.0f + fminf(e0, LIM), B  = 1.0f + fminf(e1, LIM);
            float Cq = 1.0f + fminf(e2, LIM), Dq = 1.0f + fminf(e3, LIM);
            float sAB = A + B,  sCD = Cq + Dq;
            float pAB = A * B,  pCD = Cq * Dq;
            float num = sAB * pCD + sCD * pAB;
            rs[k] += num * __builtin_amdgcn_rcpf(pAB * pCD);
            if (k != 11 && k != 23) { e0 *= R; e1 *= R; e2 *= R; e3 *= R; }
        }
    }
#pragma unroll
    for (int k = 0; k < NF; ++k)
#pragma unroll
        for (int o = 1; o < 64; o <<= 1) rs[k] += __shfl_xor(rs[k], o);
    __shared__ float red[4][NF];
    if (lane == 0) {
#pragma unroll
        for (int k = 0; k < NF; ++k) red[w][k] = rs[k];
    }
    __syncthreads();
    if (half == 0 && lane == 0) {
#pragma unroll
        for (int k = 0; k < NF; ++k)
            deg[(size_t)row * NF + k] = red[w][k] + red[w + 1][k];
    }
}

// ============================ PATH B (small ws) ============================
// pass 1: min/max of off-diag squared distance (round-1, verified)
__global__ __launch_bounds__(256) void k_minmax(const ushort* __restrict__ Eb,
                                                const float* __restrict__ sq,
                                                unsigned* __restrict__ mm) {
    const int rb = blockIdx.y, cb = blockIdx.x;
    if (cb < rb) return;
    __shared__ ushort As[128 * 32], Bs[128 * 32];
    __shared__ float sqr[128], sqc[128];
    __shared__ float red[8];
    const int tid = threadIdx.x;
    if (tid < 128) sqr[tid] = sq[rb * 128 + tid];
    else           sqc[tid - 128] = sq[cb * 128 + (tid - 128)];
    f32x4 acc[2][8];
#pragma unroll
    for (int bi = 0; bi < 2; ++bi)
#pragma unroll
        for (int bj = 0; bj < 8; ++bj) acc[bi][bj] = (f32x4){0.f, 0.f, 0.f, 0.f};
    gram_tile(Eb, rb, cb, As, Bs, acc);
    const int w = tid >> 6, lane = tid & 63, g = lane >> 4, l15 = lane & 15;
    const float sr0 = sqr[w * 32 + l15], sr1 = sqr[w * 32 + 16 + l15];
    float mn = 3.4e38f, mx = 0.0f;
#pragma unroll
    for (int bi = 0; bi < 2; ++bi)
#pragma unroll
        for (int bj = 0; bj < 8; ++bj)
#pragma unroll
            for (int m = 0; m < 4; ++m) {
                int tr = w * 32 + bi * 16 + l15;
                int tc = bj * 16 + g * 4 + m;
                float d2 = (bi ? sr1 : sr0) + sqc[tc] - 2.0f * acc[bi][bj][m];
                d2 = fmaxf(d2, 0.0f);
                bool diag = (rb == cb) && (tr == tc);
                mn = diag ? mn : fminf(mn, d2);
                mx = diag ? mx : fmaxf(mx, d2);
            }
#pragma unroll
    for (int s = 1; s < 64; s <<= 1) {
        mn = fminf(mn, __shfl_xor(mn, s));
        mx = fmaxf(mx, __shfl_xor(mx, s));
    }
    if (lane == 0) { red[w] = mn; red[4 + w] = mx; }
    __syncthreads();
    if (tid == 0) {
        mn = fminf(fminf(red[0], red[1]), fminf(red[2], red[3]));
        mx = fmaxf(fmaxf(red[4], red[5]), fmaxf(red[6], red[7]));
        atomicMin(&mm[0], __float_as_uint(mn));
        atomicMax(&mm[1], __float_as_uint(mx));
    }
}

// pass 2: gram recompute + recurrence sigmoid (in-place fallback)
__global__ __launch_bounds__(256) void k_accum2(const ushort* __restrict__ Eb,
                                                const float* __restrict__ sq,
                                                const unsigned* __restrict__ mm,
                                                float* __restrict__ deg) {
    const int rb = blockIdx.y, cb = blockIdx.x;
    __shared__ ushort As[128 * 32], Bs[128 * 32];
    __shared__ float sqr[128], sqc[128];
    __shared__ float degr[128][NF];
    const int tid = threadIdx.x;
    if (tid < 128) sqr[tid] = sq[rb * 128 + tid];
    else           sqc[tid - 128] = sq[cb * 128 + (tid - 128)];
    for (int i = tid; i < 128 * NF; i += 256) ((float*)degr)[i] = 0.0f;
    f32x4 acc[2][8];
#pragma unroll
    for (int bi = 0; bi < 2; ++bi)
#pragma unroll
        for (int bj = 0; bj < 8; ++bj) acc[bi][bj] = (f32x4){0.f, 0.f, 0.f, 0.f};
    gram_tile(Eb, rb, cb, As, Bs, acc);
    const int w = tid >> 6, lane = tid & 63, g = lane >> 4, l15 = lane & 15;

    const float dmin2 = __uint_as_float(mm[0]);
    const float dmax2 = __uint_as_float(mm[1]);
    const float d_min = dmin2 > 1e-12f ? sqrtf(dmin2) : 0.0f;
    const float d_mx  = dmax2 > 1e-12f ? sqrtf(dmax2) : 0.0f;
    const float d_max = fmaxf(d_mx, d_min + 1e-4f);
    const float stp   = (d_max - d_min) / 23.0f;
    const float S2L   = (1.0f / 0.15f) * 1.44269504f;
    const float Ds2   = stp * S2L;
    const float R     = __builtin_amdgcn_exp2f(-Ds2);
    const float LIM   = 1073741824.0f;  // 2^30
    const float ECAP  = 125.0f;

    const float sr0 = sqr[w * 32 + l15], sr1 = sqr[w * 32 + 16 + l15];
    f32x4 ee[2][8];
#pragma unroll
    for (int bi = 0; bi < 2; ++bi)
#pragma unroll
        for (int bj = 0; bj < 8; ++bj)
#pragma unroll
            for (int m = 0; m < 4; ++m) {
                int tr = w * 32 + bi * 16 + l15;
                int tc = bj * 16 + g * 4 + m;
                float d2 = (bi ? sr1 : sr0) + sqc[tc] - 2.0f * acc[bi][bj][m];
                d2 = fmaxf(d2, 0.0f);
                float d = d2 > 1e-12f ? sqrtf(d2) : 0.0f;
                if (rb == cb && tr == tc) d = 1e9f;
                ee[bi][bj][m] = __builtin_amdgcn_exp2f(fminf((d - d_min) * S2L, ECAP));
            }

#pragma unroll 1
    for (int t = 0; t < NF; ++t) {
        float rs0 = 0.0f, rs1 = 0.0f;
#pragma unroll
        for (int bj = 0; bj < 8; ++bj) {
            {
                f32x4 q = ee[0][bj];
                float A  = 1.0f + fminf(q.x, LIM), B  = 1.0f + fminf(q.y, LIM);
                float Cq = 1.0f + fminf(q.z, LIM), Dq = 1.0f + fminf(q.w, LIM);
                float sAB = A + B,  sCD = Cq + Dq;
                float pAB = A * B,  pCD = Cq * Dq;
                rs0 += (sAB * pCD + sCD * pAB) * __builtin_amdgcn_rcpf(pAB * pCD);
                ee[0][bj] = q * R;
            }
            {
                f32x4 q = ee[1][bj];
                float A  = 1.0f + fminf(q.x, LIM), B  = 1.0f + fminf(q.y, LIM);
                float Cq = 1.0f + fminf(q.z, LIM), Dq = 1.0f + fminf(q.w, LIM);
                float sAB = A + B,  sCD = Cq + Dq;
                float pAB = A * B,  pCD = Cq * Dq;
                rs1 += (sAB * pCD + sCD * pAB) * __builtin_amdgcn_rcpf(pAB * pCD);
                ee[1][bj] = q * R;
            }
        }
        rs0 += __shfl_xor(rs0, 16); rs0 += __shfl_xor(rs0, 32);
        rs1 += __shfl_xor(rs1, 16); rs1 += __shfl_xor(rs1, 32);
        if (g == 0) {
            degr[w * 32 + l15][t]      += rs0;
            degr[w * 32 + 16 + l15][t] += rs1;
        }
    }
    __syncthreads();
    for (int i = tid; i < 128 * NF; i += 256) {
        int r = i / NF, t = i % NF;
        atomicAdd(&deg[(size_t)(rb * 128 + r) * NF + t], degr[r][t]);
    }
}

// ---------------- finalize ----------------
__global__ __launch_bounds__(256) void k_final(const float* __restrict__ deg,
                                               float* __restrict__ out) {
    const int tid = threadIdx.x;
    float s[NF], cnt[8];
#pragma unroll
    for (int t = 0; t < NF; ++t) s[t] = 0.0f;
#pragma unroll
    for (int k = 0; k < 8; ++k) cnt[k] = 0.0f;
    for (int i = tid; i < NPTS; i += 256) {
        const float* row = deg + (size_t)i * NF;
#pragma unroll
        for (int t = 0; t < NF; ++t) {
            float v = row[t];
            s[t] += v;
            if (t >= 16) cnt[t - 16] += (v < 0.5f) ? 1.0f : 0.0f;
        }
    }
#pragma unroll
    for (int t = 0; t < NF; ++t)
#pragma unroll
        for (int o = 1; o < 64; o <<= 1) s[t] += __shfl_xor(s[t], o);
#pragma unroll
    for (int k = 0; k < 8; ++k)
#pragma unroll
        for (int o = 1; o < 64; o <<= 1) cnt[k] += __shfl_xor(cnt[k], o);
    __shared__ float red[4][32];
    const int w = tid >> 6, lane = tid & 63;
    if (lane == 0) {
#pragma unroll
        for (int t = 0; t < NF; ++t) red[w][t] = s[t];
#pragma unroll
        for (int k = 0; k < 8; ++k) red[w][NF + k] = cnt[k];
    }
    __syncthreads();
    if (tid == 0) {
        float h0 = 0.0f, h1 = 0.0f;
#pragma unroll
        for (int t = 0; t < NF; ++t) {
            float S = red[0][t] + red[1][t] + red[2][t] + red[3][t];
            float edges = S * 0.5f;
            h1 += fmaxf(edges - (float)(NPTS - 1), 0.0f) / (float)NPTS;
        }
#pragma unroll
        for (int k = 0; k < 8; ++k)
            h0 += red[0][NF + k] + red[1][NF + k] + red[2][NF + k] + red[3][NF + k];
        h0 *= (1.0f / 8.0f);
        h1 *= (1.0f / 24.0f);
        out[0] = (h0 + 0.5f * h1) * 0.1f;
    }
}

extern "C" void kernel_launch(void* const* d_in, const int* in_sizes, int n_in,
                              void* d_out, int out_size, void* d_ws, size_t ws_size,
                              hipStream_t stream) {
    (void)in_sizes; (void)n_in; (void)out_size;
    const float* emb = (const float*)d_in[0];
    uint8_t* ws = (uint8_t*)d_ws;
    ushort*   Eb  = (ushort*)(ws);
    float*    sqv = (float*)(ws + OFF_SQ);
    unsigned* mm  = (unsigned*)(ws + OFF_MM);
    float*    deg = (float*)(ws + OFF_DEG);
    float*    D   = (float*)(ws + OFF_D);
    float*    out = (float*)d_out;
    const bool bigws = (ws_size >= WS_A);

    k_init   <<<dim3(384),      dim3(256), 0, stream>>>(deg, mm);
    k_convert<<<dim3(NPTS / 4), dim3(256), 0, stream>>>(emb, Eb, sqv);
    if (bigws) {
        k_gramstore<<<dim3(NBLK, NBLK), dim3(256), 0, stream>>>(Eb, sqv, mm, D);
        k_sig      <<<dim3(NPTS / 2),   dim3(256), 0, stream>>>(D, mm, deg);
    } else {
        k_minmax<<<dim3(NBLK, NBLK), dim3(256), 0, stream>>>(Eb, sqv, mm);
        k_accum2<<<dim3(NBLK, NBLK), dim3(256), 0, stream>>>(Eb, sqv, mm, deg);
    }
    k_final<<<1, 256, 0, stream>>>(deg, out);
}

// Round 3
// 123.687 us; speedup vs baseline: 1.4533x; 1.0136x over previous
//
#include <hip/hip_runtime.h>
#include <stdint.h>

typedef float f32x4 __attribute__((ext_vector_type(4)));
typedef short s16x8 __attribute__((ext_vector_type(8)));
typedef unsigned short us4 __attribute__((ext_vector_type(4)));

#define NPTS 4096
#define DDIM 512
#define NF   24

// ---------------- ws layout ----------------
// Eb  @ 0          : 4,194,304  (bf16 E)
// sq  @ 4,194,304  : 16,384     (f32 row sum-of-squares)
// mm  @ 4,210,688  : 64         (d2min bits, d2max bits)
// deg @ 4,210,752  : 393,216    (f32 [4096][24])
// D2h @ 4,603,968  : 33,554,432 (f16 [4096][4096] squared distances, path A)
#define OFF_SQ  4194304
#define OFF_MM  4210688
#define OFF_DEG 4210752
#define OFF_D   4603968
#define WS_A    38158400ULL

static __device__ __forceinline__ ushort f2h(float x) {
    _Float16 h = (_Float16)x;
    return __builtin_bit_cast(unsigned short, h);
}
static __device__ __forceinline__ float h2f(ushort u) {
    return (float)__builtin_bit_cast(_Float16, u);
}

// ---------------- init ----------------
__global__ __launch_bounds__(256) void k_init(float* __restrict__ deg,
                                              unsigned* __restrict__ mm) {
    int i = blockIdx.x * 256 + threadIdx.x;
    if (i < NPTS * NF) deg[i] = 0.0f;   // needed by path B only (cheap)
    if (i == 0) { mm[0] = 0x7F7FFFFFu; mm[1] = 0u; }
}

// ---------------- convert f32 -> bf16 (RNE), rowwise sum of squares --------
__global__ __launch_bounds__(256) void k_convert(const float* __restrict__ in,
                                                 ushort* __restrict__ Eb,
                                                 float* __restrict__ sq) {
    const int w = threadIdx.x >> 6, lane = threadIdx.x & 63;
    const int row = blockIdx.x * 4 + w;
    const float* src = in + (size_t)row * DDIM + lane * 8;
    float4 a = ((const float4*)src)[0];
    float4 b = ((const float4*)src)[1];
    float v[8] = {a.x, a.y, a.z, a.w, b.x, b.y, b.z, b.w};
    unsigned u[8];
    float ss = 0.0f;
#pragma unroll
    for (int i = 0; i < 8; ++i) {
        ss += v[i] * v[i];
        unsigned bits = __float_as_uint(v[i]);
        u[i] = (bits + 0x7FFFu + ((bits >> 16) & 1u)) >> 16;  // RNE to bf16
    }
    uint4 pk;
    pk.x = u[0] | (u[1] << 16);
    pk.y = u[2] | (u[3] << 16);
    pk.z = u[4] | (u[5] << 16);
    pk.w = u[6] | (u[7] << 16);
    *(uint4*)(Eb + (size_t)row * DDIM + lane * 8) = pk;
#pragma unroll
    for (int s = 1; s < 64; s <<= 1) ss += __shfl_xor(ss, s);
    if (lane == 0) sq[row] = ss;
}

// ============================ PATH A (big ws) ==============================
// 64x128 tiles, padded LDS (80B rows), f16 d2 out (full matrix via mirror),
// global min/max of off-diag d2. Keep tile iff it touches the upper triangle.
__global__ __launch_bounds__(256) void k_gram64(const ushort* __restrict__ Eb,
                                                const float* __restrict__ sq,
                                                unsigned* __restrict__ mm,
                                                ushort* __restrict__ D2h) {
    const int cbt = blockIdx.x;   // 128-col tile, 0..31
    const int rbt = blockIdx.y;   // 64-row tile, 0..63
    if (rbt > 2 * cbt + 1) return;  // tile entirely below diagonal
    __shared__ ushort As[64 * 40], Bs[128 * 40];  // 80B rows: 2-way-ish banks
    __shared__ float sqr[64], sqc[128], red[8];
    const int tid = threadIdx.x;
    const int w = tid >> 6, lane = tid & 63, g = lane >> 4, l15 = lane & 15;
    if (tid < 128) sqc[tid] = sq[cbt * 128 + tid];
    else if (tid >= 192) sqr[tid - 192] = sq[rbt * 64 + (tid - 192)];

    f32x4 acc[8];
#pragma unroll
    for (int bj = 0; bj < 8; ++bj) acc[bj] = (f32x4){0.f, 0.f, 0.f, 0.f};

    const int srow = tid >> 2, sch = tid & 3;
#pragma unroll 1
    for (int kk = 0; kk < DDIM / 32; ++kk) {
        const int k0 = kk * 32;
        __syncthreads();
        uint4 va  = *(const uint4*)(Eb + (size_t)(rbt * 64 + srow) * DDIM + k0 + sch * 8);
        uint4 vb0 = *(const uint4*)(Eb + (size_t)(cbt * 128 + srow) * DDIM + k0 + sch * 8);
        uint4 vb1 = *(const uint4*)(Eb + (size_t)(cbt * 128 + 64 + srow) * DDIM + k0 + sch * 8);
        *(uint4*)(As + srow * 40 + sch * 8) = va;
        *(uint4*)(Bs + srow * 40 + sch * 8) = vb0;
        *(uint4*)(Bs + (64 + srow) * 40 + sch * 8) = vb1;
        __syncthreads();
        s16x8 rf = *(const s16x8*)(As + (w * 16 + l15) * 40 + g * 8);
#pragma unroll
        for (int bj = 0; bj < 8; ++bj) {
            s16x8 cf = *(const s16x8*)(Bs + (bj * 16 + l15) * 40 + g * 8);
            acc[bj] = __builtin_amdgcn_mfma_f32_16x16x32_bf16(cf, rf, acc[bj], 0, 0, 0);
        }
    }

    const int tr = rbt * 64 + w * 16 + l15;
    const float srv = sqr[w * 16 + l15];
    float mn = 3.4e38f, mx = 0.0f;
#pragma unroll
    for (int bj = 0; bj < 8; ++bj) {
        const int c0 = bj * 16 + g * 4;
        const int tc0 = cbt * 128 + c0;
        ushort h[4];
#pragma unroll
        for (int m = 0; m < 4; ++m) {
            float d2 = srv + sqc[c0 + m] - 2.0f * acc[bj][m];
            d2 = fmaxf(d2, 0.0f);
            bool diag = (tc0 + m == tr);
            mn = diag ? mn : fminf(mn, d2);
            mx = diag ? mx : fmaxf(mx, d2);
            h[m] = f2h(diag ? 6.0e4f : d2);   // diag -> huge d2 -> sigma == 0
        }
        if (tc0 > tr) {                       // strictly upper: packed + mirror
            us4 pk = {h[0], h[1], h[2], h[3]};
            *(us4*)(D2h + (size_t)tr * NPTS + tc0) = pk;
#pragma unroll
            for (int m = 0; m < 4; ++m)
                D2h[(size_t)(tc0 + m) * NPTS + tr] = h[m];
        } else if (tc0 + 3 >= tr) {           // straddles diagonal
#pragma unroll
            for (int m = 0; m < 4; ++m) {
                int tc = tc0 + m;
                if (tc > tr) {
                    D2h[(size_t)tr * NPTS + tc] = h[m];
                    D2h[(size_t)tc * NPTS + tr] = h[m];
                } else if (tc == tr) {
                    D2h[(size_t)tr * NPTS + tc] = h[m];
                }
            }
        } // tc0+3 < tr: below diagonal, mirror twin stores it
    }
#pragma unroll
    for (int s = 1; s < 64; s <<= 1) {
        mn = fminf(mn, __shfl_xor(mn, s));
        mx = fmaxf(mx, __shfl_xor(mx, s));
    }
    if (lane == 0) { red[w] = mn; red[4 + w] = mx; }
    __syncthreads();
    if (tid == 0) {
        mn = fminf(fminf(red[0], red[1]), fminf(red[2], red[3]));
        mx = fmaxf(fmaxf(red[4], red[5]), fmaxf(red[6], red[7]));
        atomicMin(&mm[0], __float_as_uint(mn));  // nonneg: bit order == value order
        atomicMax(&mm[1], __float_as_uint(mx));
    }
}

// pass 2: stream f16 d2, geometric-recurrence sigmoid, 4-way batched rcp.
// Wave = half a row (2048 entries, 8 f16 per lane per load).
__global__ __launch_bounds__(256) void k_sig2(const ushort* __restrict__ D2h,
                                              const unsigned* __restrict__ mm,
                                              float* __restrict__ deg) {
    const int tid = threadIdx.x, w = tid >> 6, lane = tid & 63;
    const int row  = blockIdx.x * 2 + (w >> 1);
    const int half = w & 1;

    const float dmin2 = __uint_as_float(mm[0]);
    const float dmax2 = __uint_as_float(mm[1]);
    const float d_min = dmin2 > 1e-12f ? __builtin_amdgcn_sqrtf(dmin2) : 0.0f;
    const float d_mx  = dmax2 > 1e-12f ? __builtin_amdgcn_sqrtf(dmax2) : 0.0f;
    const float d_max = fmaxf(d_mx, d_min + 1e-4f);
    const float stp   = (d_max - d_min) / 23.0f;
    const float S2L   = (1.0f / 0.15f) * 1.44269504f;   // invT * log2(e)
    const float C0    = d_min * S2L;
    const float Ds2   = stp * S2L;
    const float C12   = C0 + 12.0f * Ds2;
    const float R     = __builtin_amdgcn_exp2f(-Ds2);
    const float LIM   = 1073741824.0f;  // 2^30
    const float ECAP  = 125.0f;

    float rs[NF];
#pragma unroll
    for (int k = 0; k < NF; ++k) rs[k] = 0.0f;

    const ushort* base = D2h + (size_t)row * NPTS + half * 2048 + lane * 8;
#pragma unroll 1
    for (int c = 0; c < 4; ++c) {
        uint4 pk = *(const uint4*)(base + c * 512);
        unsigned pw[4] = {pk.x, pk.y, pk.z, pk.w};
        float u[8];
#pragma unroll
        for (int i = 0; i < 4; ++i) {
            float d2a = h2f((ushort)(pw[i] & 0xFFFFu));
            float d2b = h2f((ushort)(pw[i] >> 16));
            u[2 * i]     = __builtin_amdgcn_sqrtf(d2a) * S2L;
            u[2 * i + 1] = __builtin_amdgcn_sqrtf(d2b) * S2L;
        }
        float e[8];
#pragma unroll
        for (int i = 0; i < 8; ++i)
            e[i] = __builtin_amdgcn_exp2f(fminf(u[i] - C0, ECAP));
#pragma unroll
        for (int k = 0; k < NF; ++k) {
            if (k == 12) {  // re-anchor: precision/overflow safety
#pragma unroll
                for (int i = 0; i < 8; ++i)
                    e[i] = __builtin_amdgcn_exp2f(fminf(u[i] - C12, ECAP));
            }
#pragma unroll
            for (int q = 0; q < 2; ++q) {
                float A  = 1.0f + fminf(e[4 * q + 0], LIM);
                float B  = 1.0f + fminf(e[4 * q + 1], LIM);
                float Cq = 1.0f + fminf(e[4 * q + 2], LIM);
                float Dq = 1.0f + fminf(e[4 * q + 3], LIM);
                float sAB = A + B,  sCD = Cq + Dq;
                float pAB = A * B,  pCD = Cq * Dq;
                float num = sAB * pCD + sCD * pAB;
                rs[k] += num * __builtin_amdgcn_rcpf(pAB * pCD);
            }
            if (k != 11 && k != 23) {
#pragma unroll
                for (int i = 0; i < 8; ++i) e[i] *= R;
            }
        }
    }
#pragma unroll
    for (int k = 0; k < NF; ++k)
#pragma unroll
        for (int o = 1; o < 64; o <<= 1) rs[k] += __shfl_xor(rs[k], o);
    __shared__ float red[4][NF];
    if (lane == 0) {
#pragma unroll
        for (int k = 0; k < NF; ++k) red[w][k] = rs[k];
    }
    __syncthreads();
    if (half == 0 && lane == 0) {
#pragma unroll
        for (int k = 0; k < NF; ++k)
            deg[(size_t)row * NF + k] = red[w][k] + red[w + 1][k];
    }
}

// ============================ PATH B (small ws, round-1-verified) ==========
__device__ __forceinline__ void gram_tile(const ushort* __restrict__ Eb, int rb, int cb,
                                          ushort* As, ushort* Bs, f32x4 acc[2][8]) {
    const int tid = threadIdx.x;
    const int w = tid >> 6, lane = tid & 63, g = lane >> 4, l15 = lane & 15;
#pragma unroll 1
    for (int kk = 0; kk < DDIM / 32; ++kk) {
        const int k0 = kk * 32;
        __syncthreads();
#pragma unroll
        for (int it = 0; it < 2; ++it) {
            int li  = it * 256 + tid;
            int row = li >> 2, ch = li & 3;
            uint4 va = *(const uint4*)(Eb + (size_t)(rb * 128 + row) * DDIM + k0 + ch * 8);
            uint4 vb = *(const uint4*)(Eb + (size_t)(cb * 128 + row) * DDIM + k0 + ch * 8);
            *(uint4*)(As + row * 32 + ch * 8) = va;
            *(uint4*)(Bs + row * 32 + ch * 8) = vb;
        }
        __syncthreads();
        s16x8 rf0 = *(const s16x8*)(As + (w * 32 + 0 * 16 + l15) * 32 + g * 8);
        s16x8 rf1 = *(const s16x8*)(As + (w * 32 + 1 * 16 + l15) * 32 + g * 8);
#pragma unroll
        for (int bj = 0; bj < 8; ++bj) {
            s16x8 cf = *(const s16x8*)(Bs + (bj * 16 + l15) * 32 + g * 8);
            acc[0][bj] = __builtin_amdgcn_mfma_f32_16x16x32_bf16(cf, rf0, acc[0][bj], 0, 0, 0);
            acc[1][bj] = __builtin_amdgcn_mfma_f32_16x16x32_bf16(cf, rf1, acc[1][bj], 0, 0, 0);
        }
    }
}

__global__ __launch_bounds__(256) void k_minmax(const ushort* __restrict__ Eb,
                                                const float* __restrict__ sq,
                                                unsigned* __restrict__ mm) {
    const int rb = blockIdx.y, cb = blockIdx.x;
    if (cb < rb) return;
    __shared__ ushort As[128 * 32], Bs[128 * 32];
    __shared__ float sqr[128], sqc[128];
    __shared__ float red[8];
    const int tid = threadIdx.x;
    if (tid < 128) sqr[tid] = sq[rb * 128 + tid];
    else           sqc[tid - 128] = sq[cb * 128 + (tid - 128)];
    f32x4 acc[2][8];
#pragma unroll
    for (int bi = 0; bi < 2; ++bi)
#pragma unroll
        for (int bj = 0; bj < 8; ++bj) acc[bi][bj] = (f32x4){0.f, 0.f, 0.f, 0.f};
    gram_tile(Eb, rb, cb, As, Bs, acc);
    const int w = tid >> 6, lane = tid & 63, g = lane >> 4, l15 = lane & 15;
    const float sr0 = sqr[w * 32 + l15], sr1 = sqr[w * 32 + 16 + l15];
    float mn = 3.4e38f, mx = 0.0f;
#pragma unroll
    for (int bi = 0; bi < 2; ++bi)
#pragma unroll
        for (int bj = 0; bj < 8; ++bj)
#pragma unroll
            for (int m = 0; m < 4; ++m) {
                int tr = w * 32 + bi * 16 + l15;
                int tc = bj * 16 + g * 4 + m;
                float d2 = (bi ? sr1 : sr0) + sqc[tc] - 2.0f * acc[bi][bj][m];
                d2 = fmaxf(d2, 0.0f);
                bool diag = (rb == cb) && (tr == tc);
                mn = diag ? mn : fminf(mn, d2);
                mx = diag ? mx : fmaxf(mx, d2);
            }
#pragma unroll
    for (int s = 1; s < 64; s <<= 1) {
        mn = fminf(mn, __shfl_xor(mn, s));
        mx = fmaxf(mx, __shfl_xor(mx, s));
    }
    if (lane == 0) { red[w] = mn; red[4 + w] = mx; }
    __syncthreads();
    if (tid == 0) {
        mn = fminf(fminf(red[0], red[1]), fminf(red[2], red[3]));
        mx = fmaxf(fmaxf(red[4], red[5]), fmaxf(red[6], red[7]));
        atomicMin(&mm[0], __float_as_uint(mn));
        atomicMax(&mm[1], __float_as_uint(mx));
    }
}

__global__ __launch_bounds__(256) void k_accum2(const ushort* __restrict__ Eb,
                                                const float* __restrict__ sq,
                                                const unsigned* __restrict__ mm,
                                                float* __restrict__ deg) {
    const int rb = blockIdx.y, cb = blockIdx.x;
    __shared__ ushort As[128 * 32], Bs[128 * 32];
    __shared__ float sqr[128], sqc[128];
    __shared__ float degr[128][NF];
    const int tid = threadIdx.x;
    if (tid < 128) sqr[tid] = sq[rb * 128 + tid];
    else           sqc[tid - 128] = sq[cb * 128 + (tid - 128)];
    for (int i = tid; i < 128 * NF; i += 256) ((float*)degr)[i] = 0.0f;
    f32x4 acc[2][8];
#pragma unroll
    for (int bi = 0; bi < 2; ++bi)
#pragma unroll
        for (int bj = 0; bj < 8; ++bj) acc[bi][bj] = (f32x4){0.f, 0.f, 0.f, 0.f};
    gram_tile(Eb, rb, cb, As, Bs, acc);
    const int w = tid >> 6, lane = tid & 63, g = lane >> 4, l15 = lane & 15;

    const float dmin2 = __uint_as_float(mm[0]);
    const float dmax2 = __uint_as_float(mm[1]);
    const float d_min = dmin2 > 1e-12f ? sqrtf(dmin2) : 0.0f;
    const float d_mx  = dmax2 > 1e-12f ? sqrtf(dmax2) : 0.0f;
    const float d_max = fmaxf(d_mx, d_min + 1e-4f);
    const float stp   = (d_max - d_min) / 23.0f;
    const float S2L   = (1.0f / 0.15f) * 1.44269504f;
    const float Ds2   = stp * S2L;
    const float R     = __builtin_amdgcn_exp2f(-Ds2);
    const float LIM   = 1073741824.0f;
    const float ECAP  = 125.0f;

    const float sr0 = sqr[w * 32 + l15], sr1 = sqr[w * 32 + 16 + l15];
    f32x4 ee[2][8];
#pragma unroll
    for (int bi = 0; bi < 2; ++bi)
#pragma unroll
        for (int bj = 0; bj < 8; ++bj)
#pragma unroll
            for (int m = 0; m < 4; ++m) {
                int tr = w * 32 + bi * 16 + l15;
                int tc = bj * 16 + g * 4 + m;
                float d2 = (bi ? sr1 : sr0) + sqc[tc] - 2.0f * acc[bi][bj][m];
                d2 = fmaxf(d2, 0.0f);
                float d = d2 > 1e-12f ? sqrtf(d2) : 0.0f;
                if (rb == cb && tr == tc) d = 1e9f;
                ee[bi][bj][m] = __builtin_amdgcn_exp2f(fminf((d - d_min) * S2L, ECAP));
            }

#pragma unroll 1
    for (int t = 0; t < NF; ++t) {
        float rs0 = 0.0f, rs1 = 0.0f;
#pragma unroll
        for (int bj = 0; bj < 8; ++bj) {
            {
                f32x4 q = ee[0][bj];
                float A  = 1.0f + fminf(q.x, LIM), B  = 1.0f + fminf(q.y, LIM);
                float Cq = 1.0f + fminf(q.z, LIM), Dq = 1.0f + fminf(q.w, LIM);
                float sAB = A + B,  sCD = Cq + Dq;
                float pAB = A * B,  pCD = Cq * Dq;
                rs0 += (sAB * pCD + sCD * pAB) * __builtin_amdgcn_rcpf(pAB * pCD);
                ee[0][bj] = q * R;
            }
            {
                f32x4 q = ee[1][bj];
                float A  = 1.0f + fminf(q.x, LIM), B  = 1.0f + fminf(q.y, LIM);
                float Cq = 1.0f + fminf(q.z, LIM), Dq = 1.0f + fminf(q.w, LIM);
                float sAB = A + B,  sCD = Cq + Dq;
                float pAB = A * B,  pCD = Cq * Dq;
                rs1 += (sAB * pCD + sCD * pAB) * __builtin_amdgcn_rcpf(pAB * pCD);
                ee[1][bj] = q * R;
            }
        }
        rs0 += __shfl_xor(rs0, 16); rs0 += __shfl_xor(rs0, 32);
        rs1 += __shfl_xor(rs1, 16); rs1 += __shfl_xor(rs1, 32);
        if (g == 0) {
            degr[w * 32 + l15][t]      += rs0;
            degr[w * 32 + 16 + l15][t] += rs1;
        }
    }
    __syncthreads();
    for (int i = tid; i < 128 * NF; i += 256) {
        int r = i / NF, t = i % NF;
        atomicAdd(&deg[(size_t)(rb * 128 + r) * NF + t], degr[r][t]);
    }
}

// ---------------- finalize ----------------
__global__ __launch_bounds__(256) void k_final(const float* __restrict__ deg,
                                               float* __restrict__ out) {
    const int tid = threadIdx.x;
    float s[NF], cnt[8];
#pragma unroll
    for (int t = 0; t < NF; ++t) s[t] = 0.0f;
#pragma unroll
    for (int k = 0; k < 8; ++k) cnt[k] = 0.0f;
    for (int i = tid; i < NPTS; i += 256) {
        const float* row = deg + (size_t)i * NF;
#pragma unroll
        for (int t = 0; t < NF; ++t) {
            float v = row[t];
            s[t] += v;
            if (t >= 16) cnt[t - 16] += (v < 0.5f) ? 1.0f : 0.0f;
        }
    }
#pragma unroll
    for (int t = 0; t < NF; ++t)
#pragma unroll
        for (int o = 1; o < 64; o <<= 1) s[t] += __shfl_xor(s[t], o);
#pragma unroll
    for (int k = 0; k < 8; ++k)
#pragma unroll
        for (int o = 1; o < 64; o <<= 1) cnt[k] += __shfl_xor(cnt[k], o);
    __shared__ float red[4][32];
    const int w = tid >> 6, lane = tid & 63;
    if (lane == 0) {
#pragma unroll
        for (int t = 0; t < NF; ++t) red[w][t] = s[t];
#pragma unroll
        for (int k = 0; k < 8; ++k) red[w][NF + k] = cnt[k];
    }
    __syncthreads();
    if (tid == 0) {
        float h0 = 0.0f, h1 = 0.0f;
#pragma unroll
        for (int t = 0; t < NF; ++t) {
            float S = red[0][t] + red[1][t] + red[2][t] + red[3][t];
            float edges = S * 0.5f;
            h1 += fmaxf(edges - (float)(NPTS - 1), 0.0f) / (float)NPTS;
        }
#pragma unroll
        for (int k = 0; k < 8; ++k)
            h0 += red[0][NF + k] + red[1][NF + k] + red[2][NF + k] + red[3][NF + k];
        h0 *= (1.0f / 8.0f);
        h1 *= (1.0f / 24.0f);
        out[0] = (h0 + 0.5f * h1) * 0.1f;
    }
}

extern "C" void kernel_launch(void* const* d_in, const int* in_sizes, int n_in,
                              void* d_out, int out_size, void* d_ws, size_t ws_size,
                              hipStream_t stream) {
    (void)in_sizes; (void)n_in; (void)out_size;
    const float* emb = (const float*)d_in[0];
    uint8_t* ws = (uint8_t*)d_ws;
    ushort*   Eb  = (ushort*)(ws);
    float*    sqv = (float*)(ws + OFF_SQ);
    unsigned* mm  = (unsigned*)(ws + OFF_MM);
    float*    deg = (float*)(ws + OFF_DEG);
    ushort*   D2h = (ushort*)(ws + OFF_D);
    float*    out = (float*)d_out;
    const bool bigws = (ws_size >= WS_A);

    k_init   <<<dim3(384),      dim3(256), 0, stream>>>(deg, mm);
    k_convert<<<dim3(NPTS / 4), dim3(256), 0, stream>>>(emb, Eb, sqv);
    if (bigws) {
        k_gram64<<<dim3(32, 64),   dim3(256), 0, stream>>>(Eb, sqv, mm, D2h);
        k_sig2  <<<dim3(NPTS / 2), dim3(256), 0, stream>>>(D2h, mm, deg);
    } else {
        k_minmax<<<dim3(32, 32), dim3(256), 0, stream>>>(Eb, sqv, mm);
        k_accum2<<<dim3(32, 32), dim3(256), 0, stream>>>(Eb, sqv, mm, deg);
    }
    k_final<<<1, 256, 0, stream>>>(deg, out);
}

// Round 4
// 92.417 us; speedup vs baseline: 1.9451x; 1.3384x over previous
//
#include <hip/hip_runtime.h>
#include <stdint.h>

typedef float f32x4 __attribute__((ext_vector_type(4)));
typedef short s16x8 __attribute__((ext_vector_type(8)));
typedef unsigned short us4 __attribute__((ext_vector_type(4)));

#define NPTS 4096
#define DDIM 512
#define NF   24
#define NBLK 32
#define NB   2048   // histogram bins

// ---------------- ws layout ----------------
// Eb  @ 0          : 4,194,304   (bf16 E)
// sq  @ 4,194,304  : 16,384      (f32 row sum-of-squares)
// mm  @ 4,210,688  : 64          (d2min bits, d2max bits)
// deg @ 4,210,752  : 393,216     (f32 [4096][24])
// D2h @ 4,603,968  : 33,554,432  (f16 [4096][4096] squared distances)
// H   @ 38,158,400 : 16,777,216  (u16 [4096][2048] per-row histograms)
#define OFF_SQ  4194304
#define OFF_MM  4210688
#define OFF_DEG 4210752
#define OFF_D   4603968
#define OFF_H   38158400ULL
#define WS_A    54935616ULL

static __device__ __forceinline__ ushort f2h(float x) {
    _Float16 h = (_Float16)x;
    return __builtin_bit_cast(unsigned short, h);
}
static __device__ __forceinline__ float h2f(ushort u) {
    return (float)__builtin_bit_cast(_Float16, u);
}

// ---------------- init ----------------
__global__ __launch_bounds__(256) void k_init(float* __restrict__ deg,
                                              unsigned* __restrict__ mm) {
    int i = blockIdx.x * 256 + threadIdx.x;
    if (i < NPTS * NF) deg[i] = 0.0f;   // path B needs zeroed deg
    if (i == 0) { mm[0] = 0x7F7FFFFFu; mm[1] = 0u; }
}

// ---------------- convert f32 -> bf16 (RNE), rowwise sum of squares --------
__global__ __launch_bounds__(256) void k_convert(const float* __restrict__ in,
                                                 ushort* __restrict__ Eb,
                                                 float* __restrict__ sq) {
    const int w = threadIdx.x >> 6, lane = threadIdx.x & 63;
    const int row = blockIdx.x * 4 + w;
    const float* src = in + (size_t)row * DDIM + lane * 8;
    float4 a = ((const float4*)src)[0];
    float4 b = ((const float4*)src)[1];
    float v[8] = {a.x, a.y, a.z, a.w, b.x, b.y, b.z, b.w};
    unsigned u[8];
    float ss = 0.0f;
#pragma unroll
    for (int i = 0; i < 8; ++i) {
        ss += v[i] * v[i];
        unsigned bits = __float_as_uint(v[i]);
        u[i] = (bits + 0x7FFFu + ((bits >> 16) & 1u)) >> 16;  // RNE to bf16
    }
    uint4 pk;
    pk.x = u[0] | (u[1] << 16);
    pk.y = u[2] | (u[3] << 16);
    pk.z = u[4] | (u[5] << 16);
    pk.w = u[6] | (u[7] << 16);
    *(uint4*)(Eb + (size_t)row * DDIM + lane * 8) = pk;
#pragma unroll
    for (int s = 1; s < 64; s <<= 1) ss += __shfl_xor(ss, s);
    if (lane == 0) sq[row] = ss;
}

// ============================ PATH A ======================================
// 128x128 upper-tri tiles; register-prefetch double-buffered staging;
// f16 d2 out via LDS transpose -> BOTH copies coalesced; global min/max.
// acc[bi][bj][m] = dot(E[rb*128 + w*32 + bi*16 + l15], E[cb*128 + bj*16 + g*4 + m])
__global__ __launch_bounds__(256) void k_gram128T(const ushort* __restrict__ Eb,
                                                  const float* __restrict__ sq,
                                                  unsigned* __restrict__ mm,
                                                  ushort* __restrict__ D2h) {
    __shared__ ushort SM[4 * 128 * 40];   // 40KB staging dbuf; reused as T[128][136]
    __shared__ float sqr[128], sqc[128], red[8];
    const int tid = threadIdx.x;
    const int w = tid >> 6, lane = tid & 63, g = lane >> 4, l15 = lane & 15;

    // decode linear upper-tri tile id -> (rb, cb), rb <= cb
    int bid = blockIdx.x, rb = 0, pre = 0;
    while (pre + (NBLK - rb) <= bid) { pre += NBLK - rb; ++rb; }
    const int cb = rb + (bid - pre);

    if (tid < 128) sqr[tid] = sq[rb * 128 + tid];
    else           sqc[tid - 128] = sq[cb * 128 + (tid - 128)];

    f32x4 acc[2][8];
#pragma unroll
    for (int bi = 0; bi < 2; ++bi)
#pragma unroll
        for (int bj = 0; bj < 8; ++bj) acc[bi][bj] = (f32x4){0.f, 0.f, 0.f, 0.f};

    // staging map: thread covers rows (tid>>2) and 64+(tid>>2), chunk tid&3
    const int srow0 = tid >> 2, srow1 = 64 + (tid >> 2), sch = tid & 3;
    const size_t aoff0 = (size_t)(rb * 128 + srow0) * DDIM + sch * 8;
    const size_t aoff1 = (size_t)(rb * 128 + srow1) * DDIM + sch * 8;
    const size_t boff0 = (size_t)(cb * 128 + srow0) * DDIM + sch * 8;
    const size_t boff1 = (size_t)(cb * 128 + srow1) * DDIM + sch * 8;

    uint4 ra0 = *(const uint4*)(Eb + aoff0);
    uint4 ra1 = *(const uint4*)(Eb + aoff1);
    uint4 qb0 = *(const uint4*)(Eb + boff0);
    uint4 qb1 = *(const uint4*)(Eb + boff1);
    {
        ushort* A0 = SM;             ushort* B0 = SM + 2 * 5120;
        *(uint4*)(A0 + srow0 * 40 + sch * 8) = ra0;
        *(uint4*)(A0 + srow1 * 40 + sch * 8) = ra1;
        *(uint4*)(B0 + srow0 * 40 + sch * 8) = qb0;
        *(uint4*)(B0 + srow1 * 40 + sch * 8) = qb1;
    }
    int cur = 0;
#pragma unroll 1
    for (int kk = 0; kk < 16; ++kk) {
        if (kk < 15) {   // prefetch next K-chunk into registers (latency hidden)
            const int k1 = (kk + 1) * 32;
            ra0 = *(const uint4*)(Eb + aoff0 + k1);
            ra1 = *(const uint4*)(Eb + aoff1 + k1);
            qb0 = *(const uint4*)(Eb + boff0 + k1);
            qb1 = *(const uint4*)(Eb + boff1 + k1);
        }
        __syncthreads();   // buf[cur] fully written
        const ushort* Ac = SM + cur * 5120;
        const ushort* Bc = SM + 2 * 5120 + cur * 5120;
        s16x8 rf0 = *(const s16x8*)(Ac + (w * 32 + l15) * 40 + g * 8);
        s16x8 rf1 = *(const s16x8*)(Ac + (w * 32 + 16 + l15) * 40 + g * 8);
#pragma unroll
        for (int bj = 0; bj < 8; ++bj) {
            s16x8 cf = *(const s16x8*)(Bc + (bj * 16 + l15) * 40 + g * 8);
            acc[0][bj] = __builtin_amdgcn_mfma_f32_16x16x32_bf16(cf, rf0, acc[0][bj], 0, 0, 0);
            acc[1][bj] = __builtin_amdgcn_mfma_f32_16x16x32_bf16(cf, rf1, acc[1][bj], 0, 0, 0);
        }
        if (kk < 15) {
            ushort* An = SM + (cur ^ 1) * 5120;
            ushort* Bn = SM + 2 * 5120 + (cur ^ 1) * 5120;
            *(uint4*)(An + srow0 * 40 + sch * 8) = ra0;
            *(uint4*)(An + srow1 * 40 + sch * 8) = ra1;
            *(uint4*)(Bn + srow0 * 40 + sch * 8) = qb0;
            *(uint4*)(Bn + srow1 * 40 + sch * 8) = qb1;
        }
        cur ^= 1;
    }
    __syncthreads();   // all staging reads done before SM is reused as T

    // epilogue: d2, minmax, f16 tile into T[128][136]
    ushort* T = SM;
    float mn = 3.4e38f, mx = 0.0f;
#pragma unroll
    for (int bi = 0; bi < 2; ++bi) {
        const int trow = rb * 128 + w * 32 + bi * 16 + l15;
        const float srv = sqr[w * 32 + bi * 16 + l15];
#pragma unroll
        for (int bj = 0; bj < 8; ++bj) {
            const int c0 = bj * 16 + g * 4;
            const int tc0 = cb * 128 + c0;
            ushort h[4];
#pragma unroll
            for (int m = 0; m < 4; ++m) {
                float d2 = srv + sqc[c0 + m] - 2.0f * acc[bi][bj][m];
                d2 = fmaxf(d2, 0.0f);
                bool diag = (tc0 + m == trow);
                mn = diag ? mn : fminf(mn, d2);
                mx = diag ? mx : fmaxf(mx, d2);
                h[m] = f2h(diag ? 6.0e4f : d2);   // diag -> huge d2 -> sigma == 0
            }
            us4 pk4 = {h[0], h[1], h[2], h[3]};
            *(us4*)(T + (w * 32 + bi * 16 + l15) * 136 + c0) = pk4;
        }
    }
#pragma unroll
    for (int s = 1; s < 64; s <<= 1) {
        mn = fminf(mn, __shfl_xor(mn, s));
        mx = fmaxf(mx, __shfl_xor(mx, s));
    }
    if (lane == 0) { red[w] = mn; red[4 + w] = mx; }
    __syncthreads();   // T complete + red complete
    if (tid == 0) {
        mn = fminf(fminf(red[0], red[1]), fminf(red[2], red[3]));
        mx = fmaxf(fmaxf(red[4], red[5]), fmaxf(red[6], red[7]));
        atomicMin(&mm[0], __float_as_uint(mn));  // nonneg: bit order == value order
        atomicMax(&mm[1], __float_as_uint(mx));
    }
    // direct coalesced copy
    const int orow = tid >> 1, oh = tid & 1;
#pragma unroll
    for (int j = 0; j < 8; ++j) {
        uint4 v = *(const uint4*)(T + orow * 136 + oh * 64 + j * 8);
        *(uint4*)(D2h + (size_t)(rb * 128 + orow) * NPTS + cb * 128 + oh * 64 + j * 8) = v;
    }
    // transposed coalesced copy (mirror) for off-diagonal tiles
    if (rb != cb) {
        const int ocol = tid >> 1;
#pragma unroll
        for (int j2 = 0; j2 < 8; ++j2) {
            unsigned pw[4];
#pragma unroll
            for (int p = 0; p < 4; ++p) {
                unsigned lo = T[(oh * 64 + j2 * 8 + 2 * p) * 136 + ocol];
                unsigned hi = T[(oh * 64 + j2 * 8 + 2 * p + 1) * 136 + ocol];
                pw[p] = lo | (hi << 16);
            }
            *(uint4*)(D2h + (size_t)(cb * 128 + ocol) * NPTS + rb * 128 + oh * 64 + j2 * 8) =
                *(uint4*)pw;
        }
    }
}

// per-row histogram of f16 d2 into NB bins over [d2min, d2max]; u16 out.
__global__ __launch_bounds__(256) void k_hist(const ushort* __restrict__ D2h,
                                              const unsigned* __restrict__ mm,
                                              ushort* __restrict__ H) {
    __shared__ unsigned hist[NB];
    const int tid = threadIdx.x;
    const int row = blockIdx.x;
    for (int i = tid; i < NB; i += 256) hist[i] = 0u;
    const float d2min = __uint_as_float(mm[0]);
    const float d2max = __uint_as_float(mm[1]);
    const float sc = (float)NB / fmaxf(d2max - d2min, 1e-6f);
    __syncthreads();
    const uint4* Dv = (const uint4*)(D2h + (size_t)row * NPTS);
#pragma unroll
    for (int c = 0; c < 2; ++c) {
        uint4 pk = Dv[c * 256 + tid];
        unsigned pw[4] = {pk.x, pk.y, pk.z, pk.w};
#pragma unroll
        for (int i = 0; i < 4; ++i) {
            float a = h2f((ushort)(pw[i] & 0xFFFFu));
            float b = h2f((ushort)(pw[i] >> 16));
            if (a < 3.0e4f) {   // excludes the diagonal marker (6e4)
                int ba = (int)fminf(fmaxf((a - d2min) * sc, 0.0f), (float)(NB - 1));
                atomicAdd(&hist[ba], 1u);
            }
            if (b < 3.0e4f) {
                int bb = (int)fminf(fmaxf((b - d2min) * sc, 0.0f), (float)(NB - 1));
                atomicAdd(&hist[bb], 1u);
            }
        }
    }
    __syncthreads();
    unsigned o[4];
#pragma unroll
    for (int p = 0; p < 4; ++p) {
        unsigned lo = hist[tid * 8 + 2 * p], hi = hist[tid * 8 + 2 * p + 1];
        o[p] = (lo & 0xFFFFu) | (hi << 16);
    }
    *(uint4*)(H + (size_t)row * NB + tid * 8) = *(uint4*)o;
}

// deg[row][k] = sum_b hist[row][b] * sigma((t_k - d_b)/T); W generated in LDS,
// 6 phases of 4 thresholds (32KB). One wave per row, 8 rows per block.
__global__ __launch_bounds__(512) void k_dot(const ushort* __restrict__ H,
                                             const unsigned* __restrict__ mm,
                                             float* __restrict__ deg) {
    __shared__ float Wl[4][NB];   // 32KB
    const int tid = threadIdx.x;
    const int wid = tid >> 6, lane = tid & 63;
    const int row = blockIdx.x * 8 + wid;

    const float d2min = __uint_as_float(mm[0]);
    const float d2max = __uint_as_float(mm[1]);
    const float bw    = fmaxf(d2max - d2min, 1e-6f) / (float)NB;
    const float d_min = d2min > 1e-12f ? sqrtf(d2min) : 0.0f;
    const float d_mx  = d2max > 1e-12f ? sqrtf(d2max) : 0.0f;
    const float d_max = fmaxf(d_mx, d_min + 1e-4f);
    const float stp   = (d_max - d_min) / 23.0f;
    const float S2L   = (1.0f / 0.15f) * 1.44269504f;   // invT * log2(e)
    const float Ds2   = stp * S2L;
    const float R     = exp2f(-Ds2);
    const float LIM   = 1073741824.0f;   // 2^30

    // load & widen this row's histogram: lane's bins = 8 groups of 4: j*256 + lane*4
    float hv[32];
    const ushort* Hr = H + (size_t)row * NB;
#pragma unroll
    for (int j = 0; j < 8; ++j) {
        uint2 pk = *(const uint2*)(Hr + j * 256 + lane * 4);
        hv[j * 4 + 0] = (float)(pk.x & 0xFFFFu);
        hv[j * 4 + 1] = (float)(pk.x >> 16);
        hv[j * 4 + 2] = (float)(pk.y & 0xFFFFu);
        hv[j * 4 + 3] = (float)(pk.y >> 16);
    }

    // W-gen state: thread owns bins tid*4+q; e advances by R across all 24 k
    float e4[4];
#pragma unroll
    for (int q = 0; q < 4; ++q) {
        const int b = tid * 4 + q;
        const float d2c = d2min + ((float)b + 0.5f) * bw;
        const float db = sqrtf(fmaxf(d2c, 0.0f));
        e4[q] = exp2f(fminf((db - d_min) * S2L, 125.0f));
    }

#pragma unroll 1
    for (int ph = 0; ph < 6; ++ph) {
        __syncthreads();   // previous phase's readers done before overwrite
#pragma unroll
        for (int k = 0; k < 4; ++k) {
            f32x4 sg;
#pragma unroll
            for (int q = 0; q < 4; ++q) {
                sg[q] = __builtin_amdgcn_rcpf(1.0f + fminf(e4[q], LIM));
                e4[q] *= R;
            }
            *(f32x4*)(&Wl[k][tid * 4]) = sg;
        }
        __syncthreads();
        float dacc[4];
#pragma unroll
        for (int k = 0; k < 4; ++k) {
            const float* Wr = &Wl[k][0];
            float s = 0.0f;
#pragma unroll
            for (int j = 0; j < 8; ++j) {
                const f32x4 wv = *(const f32x4*)(Wr + j * 256 + lane * 4);
                s += hv[j*4+0]*wv[0] + hv[j*4+1]*wv[1] + hv[j*4+2]*wv[2] + hv[j*4+3]*wv[3];
            }
            dacc[k] = s;
        }
#pragma unroll
        for (int k = 0; k < 4; ++k)
#pragma unroll
            for (int o = 1; o < 64; o <<= 1) dacc[k] += __shfl_xor(dacc[k], o);
        if (lane == 0) {
#pragma unroll
            for (int k = 0; k < 4; ++k) deg[(size_t)row * NF + ph * 4 + k] = dacc[k];
        }
    }
}

// ============================ PATH B (small ws, verified) ==================
__device__ __forceinline__ void gram_tile(const ushort* __restrict__ Eb, int rb, int cb,
                                          ushort* As, ushort* Bs, f32x4 acc[2][8]) {
    const int tid = threadIdx.x;
    const int w = tid >> 6, lane = tid & 63, g = lane >> 4, l15 = lane & 15;
#pragma unroll 1
    for (int kk = 0; kk < DDIM / 32; ++kk) {
        const int k0 = kk * 32;
        __syncthreads();
#pragma unroll
        for (int it = 0; it < 2; ++it) {
            int li  = it * 256 + tid;
            int row = li >> 2, ch = li & 3;
            uint4 va = *(const uint4*)(Eb + (size_t)(rb * 128 + row) * DDIM + k0 + ch * 8);
            uint4 vb = *(const uint4*)(Eb + (size_t)(cb * 128 + row) * DDIM + k0 + ch * 8);
            *(uint4*)(As + row * 32 + ch * 8) = va;
            *(uint4*)(Bs + row * 32 + ch * 8) = vb;
        }
        __syncthreads();
        s16x8 rf0 = *(const s16x8*)(As + (w * 32 + 0 * 16 + l15) * 32 + g * 8);
        s16x8 rf1 = *(const s16x8*)(As + (w * 32 + 1 * 16 + l15) * 32 + g * 8);
#pragma unroll
        for (int bj = 0; bj < 8; ++bj) {
            s16x8 cf = *(const s16x8*)(Bs + (bj * 16 + l15) * 32 + g * 8);
            acc[0][bj] = __builtin_amdgcn_mfma_f32_16x16x32_bf16(cf, rf0, acc[0][bj], 0, 0, 0);
            acc[1][bj] = __builtin_amdgcn_mfma_f32_16x16x32_bf16(cf, rf1, acc[1][bj], 0, 0, 0);
        }
    }
}

__global__ __launch_bounds__(256) void k_minmax(const ushort* __restrict__ Eb,
                                                const float* __restrict__ sq,
                                                unsigned* __restrict__ mm) {
    const int rb = blockIdx.y, cb = blockIdx.x;
    if (cb < rb) return;
    __shared__ ushort As[128 * 32], Bs[128 * 32];
    __shared__ float sqr[128], sqc[128];
    __shared__ float red[8];
    const int tid = threadIdx.x;
    if (tid < 128) sqr[tid] = sq[rb * 128 + tid];
    else           sqc[tid - 128] = sq[cb * 128 + (tid - 128)];
    f32x4 acc[2][8];
#pragma unroll
    for (int bi = 0; bi < 2; ++bi)
#pragma unroll
        for (int bj = 0; bj < 8; ++bj) acc[bi][bj] = (f32x4){0.f, 0.f, 0.f, 0.f};
    gram_tile(Eb, rb, cb, As, Bs, acc);
    const int w = tid >> 6, lane = tid & 63, g = lane >> 4, l15 = lane & 15;
    const float sr0 = sqr[w * 32 + l15], sr1 = sqr[w * 32 + 16 + l15];
    float mn = 3.4e38f, mx = 0.0f;
#pragma unroll
    for (int bi = 0; bi < 2; ++bi)
#pragma unroll
        for (int bj = 0; bj < 8; ++bj)
#pragma unroll
            for (int m = 0; m < 4; ++m) {
                int tr = w * 32 + bi * 16 + l15;
                int tc = bj * 16 + g * 4 + m;
                float d2 = (bi ? sr1 : sr0) + sqc[tc] - 2.0f * acc[bi][bj][m];
                d2 = fmaxf(d2, 0.0f);
                bool diag = (rb == cb) && (tr == tc);
                mn = diag ? mn : fminf(mn, d2);
                mx = diag ? mx : fmaxf(mx, d2);
            }
#pragma unroll
    for (int s = 1; s < 64; s <<= 1) {
        mn = fminf(mn, __shfl_xor(mn, s));
        mx = fmaxf(mx, __shfl_xor(mx, s));
    }
    if (lane == 0) { red[w] = mn; red[4 + w] = mx; }
    __syncthreads();
    if (tid == 0) {
        mn = fminf(fminf(red[0], red[1]), fminf(red[2], red[3]));
        mx = fmaxf(fmaxf(red[4], red[5]), fmaxf(red[6], red[7]));
        atomicMin(&mm[0], __float_as_uint(mn));
        atomicMax(&mm[1], __float_as_uint(mx));
    }
}

__global__ __launch_bounds__(256) void k_accum2(const ushort* __restrict__ Eb,
                                                const float* __restrict__ sq,
                                                const unsigned* __restrict__ mm,
                                                float* __restrict__ deg) {
    const int rb = blockIdx.y, cb = blockIdx.x;
    __shared__ ushort As[128 * 32], Bs[128 * 32];
    __shared__ float sqr[128], sqc[128];
    __shared__ float degr[128][NF];
    const int tid = threadIdx.x;
    if (tid < 128) sqr[tid] = sq[rb * 128 + tid];
    else           sqc[tid - 128] = sq[cb * 128 + (tid - 128)];
    for (int i = tid; i < 128 * NF; i += 256) ((float*)degr)[i] = 0.0f;
    f32x4 acc[2][8];
#pragma unroll
    for (int bi = 0; bi < 2; ++bi)
#pragma unroll
        for (int bj = 0; bj < 8; ++bj) acc[bi][bj] = (f32x4){0.f, 0.f, 0.f, 0.f};
    gram_tile(Eb, rb, cb, As, Bs, acc);
    const int w = tid >> 6, lane = tid & 63, g = lane >> 4, l15 = lane & 15;

    const float dmin2 = __uint_as_float(mm[0]);
    const float dmax2 = __uint_as_float(mm[1]);
    const float d_min = dmin2 > 1e-12f ? sqrtf(dmin2) : 0.0f;
    const float d_mx  = dmax2 > 1e-12f ? sqrtf(dmax2) : 0.0f;
    const float d_max = fmaxf(d_mx, d_min + 1e-4f);
    const float stp   = (d_max - d_min) / 23.0f;
    const float S2L   = (1.0f / 0.15f) * 1.44269504f;
    const float Ds2   = stp * S2L;
    const float R     = exp2f(-Ds2);
    const float LIM   = 1073741824.0f;
    const float ECAP  = 125.0f;

    const float sr0 = sqr[w * 32 + l15], sr1 = sqr[w * 32 + 16 + l15];
    f32x4 ee[2][8];
#pragma unroll
    for (int bi = 0; bi < 2; ++bi)
#pragma unroll
        for (int bj = 0; bj < 8; ++bj)
#pragma unroll
            for (int m = 0; m < 4; ++m) {
                int tr = w * 32 + bi * 16 + l15;
                int tc = bj * 16 + g * 4 + m;
                float d2 = (bi ? sr1 : sr0) + sqc[tc] - 2.0f * acc[bi][bj][m];
                d2 = fmaxf(d2, 0.0f);
                float d = d2 > 1e-12f ? sqrtf(d2) : 0.0f;
                if (rb == cb && tr == tc) d = 1e9f;
                ee[bi][bj][m] = exp2f(fminf((d - d_min) * S2L, ECAP));
            }

#pragma unroll 1
    for (int t = 0; t < NF; ++t) {
        float rs0 = 0.0f, rs1 = 0.0f;
#pragma unroll
        for (int bj = 0; bj < 8; ++bj) {
            {
                f32x4 q = ee[0][bj];
                float A  = 1.0f + fminf(q.x, LIM), B  = 1.0f + fminf(q.y, LIM);
                float Cq = 1.0f + fminf(q.z, LIM), Dq = 1.0f + fminf(q.w, LIM);
                float sAB = A + B,  sCD = Cq + Dq;
                float pAB = A * B,  pCD = Cq * Dq;
                rs0 += (sAB * pCD + sCD * pAB) * __builtin_amdgcn_rcpf(pAB * pCD);
                ee[0][bj] = q * R;
            }
            {
                f32x4 q = ee[1][bj];
                float A  = 1.0f + fminf(q.x, LIM), B  = 1.0f + fminf(q.y, LIM);
                float Cq = 1.0f + fminf(q.z, LIM), Dq = 1.0f + fminf(q.w, LIM);
                float sAB = A + B,  sCD = Cq + Dq;
                float pAB = A * B,  pCD = Cq * Dq;
                rs1 += (sAB * pCD + sCD * pAB) * __builtin_amdgcn_rcpf(pAB * pCD);
                ee[1][bj] = q * R;
            }
        }
        rs0 += __shfl_xor(rs0, 16); rs0 += __shfl_xor(rs0, 32);
        rs1 += __shfl_xor(rs1, 16); rs1 += __shfl_xor(rs1, 32);
        if (g == 0) {
            degr[w * 32 + l15][t]      += rs0;
            degr[w * 32 + 16 + l15][t] += rs1;
        }
    }
    __syncthreads();
    for (int i = tid; i < 128 * NF; i += 256) {
        int r = i / NF, t = i % NF;
        atomicAdd(&deg[(size_t)(rb * 128 + r) * NF + t], degr[r][t]);
    }
}

// ---------------- finalize ----------------
__global__ __launch_bounds__(256) void k_final(const float* __restrict__ deg,
                                               float* __restrict__ out) {
    const int tid = threadIdx.x;
    float s[NF], cnt[8];
#pragma unroll
    for (int t = 0; t < NF; ++t) s[t] = 0.0f;
#pragma unroll
    for (int k = 0; k < 8; ++k) cnt[k] = 0.0f;
    for (int i = tid; i < NPTS; i += 256) {
        const float* row = deg + (size_t)i * NF;
#pragma unroll
        for (int t = 0; t < NF; ++t) {
            float v = row[t];
            s[t] += v;
            if (t >= 16) cnt[t - 16] += (v < 0.5f) ? 1.0f : 0.0f;
        }
    }
#pragma unroll
    for (int t = 0; t < NF; ++t)
#pragma unroll
        for (int o = 1; o < 64; o <<= 1) s[t] += __shfl_xor(s[t], o);
#pragma unroll
    for (int k = 0; k < 8; ++k)
#pragma unroll
        for (int o = 1; o < 64; o <<= 1) cnt[k] += __shfl_xor(cnt[k], o);
    __shared__ float red[4][32];
    const int w = tid >> 6, lane = tid & 63;
    if (lane == 0) {
#pragma unroll
        for (int t = 0; t < NF; ++t) red[w][t] = s[t];
#pragma unroll
        for (int k = 0; k < 8; ++k) red[w][NF + k] = cnt[k];
    }
    __syncthreads();
    if (tid == 0) {
        float h0 = 0.0f, h1 = 0.0f;
#pragma unroll
        for (int t = 0; t < NF; ++t) {
            float S = red[0][t] + red[1][t] + red[2][t] + red[3][t];
            float edges = S * 0.5f;
            h1 += fmaxf(edges - (float)(NPTS - 1), 0.0f) / (float)NPTS;
        }
#pragma unroll
        for (int k = 0; k < 8; ++k)
            h0 += red[0][NF + k] + red[1][NF + k] + red[2][NF + k] + red[3][NF + k];
        h0 *= (1.0f / 8.0f);
        h1 *= (1.0f / 24.0f);
        out[0] = (h0 + 0.5f * h1) * 0.1f;
    }
}

extern "C" void kernel_launch(void* const* d_in, const int* in_sizes, int n_in,
                              void* d_out, int out_size, void* d_ws, size_t ws_size,
                              hipStream_t stream) {
    (void)in_sizes; (void)n_in; (void)out_size;
    const float* emb = (const float*)d_in[0];
    uint8_t* ws = (uint8_t*)d_ws;
    ushort*   Eb  = (ushort*)(ws);
    float*    sqv = (float*)(ws + OFF_SQ);
    unsigned* mm  = (unsigned*)(ws + OFF_MM);
    float*    deg = (float*)(ws + OFF_DEG);
    ushort*   D2h = (ushort*)(ws + OFF_D);
    ushort*   H   = (ushort*)(ws + OFF_H);
    float*    out = (float*)d_out;
    const bool bigws = (ws_size >= WS_A);

    k_init   <<<dim3(384),      dim3(256), 0, stream>>>(deg, mm);
    k_convert<<<dim3(NPTS / 4), dim3(256), 0, stream>>>(emb, Eb, sqv);
    if (bigws) {
        k_gram128T<<<dim3(NBLK * (NBLK + 1) / 2), dim3(256), 0, stream>>>(Eb, sqv, mm, D2h);
        k_hist    <<<dim3(NPTS),                  dim3(256), 0, stream>>>(D2h, mm, H);
        k_dot     <<<dim3(NPTS / 8),              dim3(512), 0, stream>>>(H, mm, deg);
    } else {
        k_minmax<<<dim3(32, 32), dim3(256), 0, stream>>>(Eb, sqv, mm);
        k_accum2<<<dim3(32, 32), dim3(256), 0, stream>>>(Eb, sqv, mm, deg);
    }
    k_final<<<1, 256, 0, stream>>>(deg, out);
}